// Round 16
// baseline (107.448 us; speedup 1.0000x reference)
//
#include <hip/hip_runtime.h>

#define B_ 16
#define C_ 256
#define P_ 2048
#define KT 8        // C_/32 K-steps

typedef __attribute__((ext_vector_type(8))) short short8;
typedef __attribute__((ext_vector_type(4))) float floatx4;

// round-to-nearest-even fp32 -> bf16
__device__ inline short f2bf(float v) {
  union { float f; unsigned u; } c; c.f = v;
  unsigned r = c.u + 0x7fffu + ((c.u >> 16) & 1u);
  return (short)(r >> 16);
}

// ---------------- fully fused: load fp32 -> convert -> Gram GEMM -> normalize ----------------
// One kernel. Reg-staged conversion replaces the transpose pass: wave w stages
// c-octet w for all 128 rows of each operand; exact fp32 norm^2 accumulated
// during conversion; single fenced lgkmcnt(0)+barrier per K-step (completes my
// ds_writes AND drains my previous frag reads -> r3-r5 completion discipline).
__global__ __launch_bounds__(256, 3) void k_fused(const float* __restrict__ x,
                                                  float* __restrict__ out) {
  // XCD-chunked: xcd = bid%8 owns 2 full batches (x slice 4.2MB -> mostly L2)
  const int bid = blockIdx.x;
  const int xcd = bid & 7;
  const int s = bid >> 3;            // 0..511
  const int b = xcd * 2 + (s >> 8);  // 2 batches per XCD
  const int t = s & 255;             // 0..255
  const int tm = t >> 4, tn = t & 15;
  const int p0 = tm * 128, q0 = tn * 128;
  const float* xb = x + (size_t)b * C_ * P_;

  __shared__ __align__(16) short As[2][128 * 32];  // [row][32c] bf16, 64B rows
  __shared__ __align__(16) short Bs[2][128 * 32];
  __shared__ float pn[4][256];                     // per-wave norm^2 partials

  const int tid = threadIdx.x;
  const int lane = tid & 63;
  const int wid = tid >> 6;   // wave = c-octet owner
  const int wrow = wid >> 1;  // p band (64) for MFMA
  const int wcol = wid & 1;   // q band (64)

  floatx4 acc[4][4];
#pragma unroll
  for (int i = 0; i < 4; ++i)
#pragma unroll
    for (int j = 0; j < 4; ++j) acc[i][j] = (floatx4){0.f, 0.f, 0.f, 0.f};

  // staging registers: 2 row-halves x 8 c each, A and B
  float av[2][8], bv[2][8];
  float nsA[2] = {0.f, 0.f}, nsB[2] = {0.f, 0.f};

  // coalesced: one instruction per (j, half) = 64 lanes x 4B contiguous (256B)
#define LOADS(kt_)                                                        \
  do {                                                                    \
    const int cb_ = (kt_)*32 + wid * 8;                                   \
    _Pragma("unroll") for (int j = 0; j < 8; ++j) {                       \
      av[0][j] = xb[(size_t)(cb_ + j) * P_ + p0 + lane];                  \
      av[1][j] = xb[(size_t)(cb_ + j) * P_ + p0 + 64 + lane];             \
      bv[0][j] = xb[(size_t)(cb_ + j) * P_ + q0 + lane];                  \
      bv[1][j] = xb[(size_t)(cb_ + j) * P_ + q0 + 64 + lane];             \
    }                                                                     \
  } while (0)

  LOADS(0);

  for (int kt = 0; kt < KT; ++kt) {
    const int cur = kt & 1;
    // convert + exact norms + stage to LDS (compiler inserts vmcnt before uses)
#pragma unroll
    for (int tt = 0; tt < 2; ++tt) {
      short8 sa, sb;
      float na = 0.f, nb = 0.f;
#pragma unroll
      for (int j = 0; j < 8; ++j) {
        const float a_ = av[tt][j], b_ = bv[tt][j];
        sa[j] = f2bf(a_);
        sb[j] = f2bf(b_);
        na += a_ * a_;
        nb += b_ * b_;
      }
      nsA[tt] += na;
      nsB[tt] += nb;
      const int row = tt * 64 + lane;
      *reinterpret_cast<short8*>(&As[cur][row * 32 + wid * 8]) = sa;
      *reinterpret_cast<short8*>(&Bs[cur][row * 32 + wid * 8]) = sb;
    }
    if (kt < KT - 1) LOADS(kt + 1);  // issue next step's loads before the barrier

    // ONE barrier per K-step: lgkmcnt(0) completes my ds_writes AND drains my
    // prior frag reads (in-order DS queue) before any wave may rewrite that
    // buffer two steps later; barrier makes it collective.
    asm volatile("s_waitcnt lgkmcnt(0)\n\ts_barrier" ::: "memory");

    short8 af[4], bf[4];
#pragma unroll
    for (int mi = 0; mi < 4; ++mi) {
      const int r = wrow * 64 + mi * 16 + (lane & 15);
      af[mi] = *reinterpret_cast<const short8*>(&As[cur][r * 32 + (lane >> 4) * 8]);
    }
#pragma unroll
    for (int ni = 0; ni < 4; ++ni) {
      const int r = wcol * 64 + ni * 16 + (lane & 15);
      bf[ni] = *reinterpret_cast<const short8*>(&Bs[cur][r * 32 + (lane >> 4) * 8]);
    }
    // D[row=p][col=q]; C/D layout: col=lane&15, row=(lane>>4)*4+reg (verified r1)
#pragma unroll
    for (int mi = 0; mi < 4; ++mi)
#pragma unroll
      for (int ni = 0; ni < 4; ++ni)
        acc[mi][ni] = __builtin_amdgcn_mfma_f32_16x16x32_bf16(af[mi], bf[ni], acc[mi][ni], 0, 0, 0);
  }

  // ---- cross-wave norm reduce: wave w holds octet-w partials for all rows ----
  pn[wid][lane] = nsA[0];
  pn[wid][64 + lane] = nsA[1];
  pn[wid][128 + lane] = nsB[0];
  pn[wid][192 + lane] = nsB[1];
  asm volatile("s_waitcnt lgkmcnt(0)\n\ts_barrier" ::: "memory");

  float* ob = out + (size_t)b * P_ * P_;
  const int cl = lane & 15, rg4 = (lane >> 4) * 4;

  float rnq[4];
#pragma unroll
  for (int ni = 0; ni < 4; ++ni) {
    const int qr = wcol * 64 + ni * 16 + cl;  // local B row
    const float n2 = pn[0][128 + qr] + pn[1][128 + qr] + pn[2][128 + qr] + pn[3][128 + qr];
    rnq[ni] = __builtin_amdgcn_rcpf(fmaxf(sqrtf(n2), 1e-4f));
  }
  floatx4 rnp[4];
#pragma unroll
  for (int mi = 0; mi < 4; ++mi) {
#pragma unroll
    for (int r = 0; r < 4; ++r) {
      const int pr = wrow * 64 + mi * 16 + rg4 + r;  // local A row
      const float n2 = pn[0][pr] + pn[1][pr] + pn[2][pr] + pn[3][pr];
      rnp[mi][r] = __builtin_amdgcn_rcpf(fmaxf(sqrtf(n2), 1e-4f));
    }
  }

  // ---- epilogue: own tile; 4 scalar stores per (mi,ni) -> 64B segments ----
#pragma unroll
  for (int mi = 0; mi < 4; ++mi) {
    const int prow = p0 + wrow * 64 + mi * 16 + rg4;
#pragma unroll
    for (int ni = 0; ni < 4; ++ni) {
      floatx4 vv = acc[mi][ni] * rnp[mi] * rnq[ni];
      const int qc = q0 + wcol * 64 + ni * 16 + cl;
      if (tm == tn) {
        const int d = qc - prow;  // diag when prow + r == qc
        if (d >= 0 && d < 4) vv[d] = 1.0f;
      }
      ob[(size_t)(prow + 0) * P_ + qc] = vv[0];
      ob[(size_t)(prow + 1) * P_ + qc] = vv[1];
      ob[(size_t)(prow + 2) * P_ + qc] = vv[2];
      ob[(size_t)(prow + 3) * P_ + qc] = vv[3];
    }
  }
}

extern "C" void kernel_launch(void* const* d_in, const int* in_sizes, int n_in,
                              void* d_out, int out_size, void* d_ws, size_t ws_size,
                              hipStream_t stream) {
  const float* x = (const float*)d_in[0];
  float* out = (float*)d_out;
  k_fused<<<dim3(16 * 16 * B_), 256, 0, stream>>>(x, out);
}

// Round 17
// 81.921 us; speedup vs baseline: 1.3116x; 1.3116x over previous
//
#include <hip/hip_runtime.h>

#define B_ 16
#define C_ 256
#define P_ 2048
#define BK 32
#define KT 8        // C_/BK
#define NT 136      // tiles per batch (120 strict-upper + 16 diag)
#define NT_OFF 120

typedef __attribute__((ext_vector_type(8))) short short8;
typedef __attribute__((ext_vector_type(4))) float floatx4;

// round-to-nearest-even fp32 -> bf16
__device__ inline short f2bf(float v) {
  union { float f; unsigned u; } c; c.f = v;
  unsigned r = c.u + 0x7fffu + ((c.u >> 16) & 1u);
  return (short)(r >> 16);
}

#define GLOAD_LDS16(g, l)                                          \
  __builtin_amdgcn_global_load_lds(                                \
      (const __attribute__((address_space(1))) void*)(g),          \
      (__attribute__((address_space(3))) void*)(l), 16, 0, 0)

// ---------------- kernel 1: transpose + fp32->bf16 + partial norms (r11/r12) ----------------
__global__ __launch_bounds__(256, 4) void k_transpose(const float* __restrict__ x,
                                                      short* __restrict__ Xt,
                                                      float* __restrict__ nrm2p) {
  __shared__ float t[2][32][133];
  __shared__ float red[8][32][4];
  const int p0 = blockIdx.x * 128, b = blockIdx.y, zc = blockIdx.z;
  const float* xb = x + (size_t)b * C_ * P_;
  short* xtb = Xt + (size_t)b * P_ * C_;
  const int tid = threadIdx.x;
  const int tx = tid & 31;
  const int cg = tid >> 5;
  floatx4 s4 = (floatx4){0.f, 0.f, 0.f, 0.f};
  const int cbase = zc * 128;
#pragma unroll 1
  for (int chunk = 0; chunk < 4; ++chunk) {
    const int c0 = cbase + chunk * 32;
    const int tb = chunk & 1;
    float4 v[4];
#pragma unroll
    for (int i = 0; i < 4; ++i)
      v[i] = *reinterpret_cast<const float4*>(&xb[(size_t)(c0 + cg + i * 8) * P_ + p0 + tx * 4]);
#pragma unroll
    for (int i = 0; i < 4; ++i) {
      *reinterpret_cast<float4*>(&t[tb][cg + i * 8][tx * 4]) = v[i];
      s4[0] += v[i].x * v[i].x;
      s4[1] += v[i].y * v[i].y;
      s4[2] += v[i].z * v[i].z;
      s4[3] += v[i].w * v[i].w;
    }
    __syncthreads();
#pragma unroll
    for (int u = 0; u < 4; ++u) {
      const int unit = tid + 256 * u;
      const int r = unit >> 3, ch = unit & 7;
      short4 w;
      w.x = f2bf(t[tb][ch * 4 + 0][r]);
      w.y = f2bf(t[tb][ch * 4 + 1][r]);
      w.z = f2bf(t[tb][ch * 4 + 2][r]);
      w.w = f2bf(t[tb][ch * 4 + 3][r]);
      *reinterpret_cast<short4*>(&xtb[(size_t)(p0 + r) * C_ + c0 + ch * 4]) = w;
    }
  }
  *reinterpret_cast<floatx4*>(&red[cg][tx][0]) = s4;
  __syncthreads();
  if (tid < 128) {
    const int cgp = tid >> 2, j = tid & 3;
    float ns = 0.f;
#pragma unroll
    for (int g = 0; g < 8; ++g) ns += red[g][cgp][j];
    nrm2p[(size_t)zc * B_ * P_ + b * P_ + p0 + tid] = ns;
  }
}

// ---------------- kernel 2: symmetric Gram GEMM, XCD-chunked + T2 LDS SWIZZLE ----------------
// SINGLE LEVER vs r12: XOR-swizzle the As/Bs slot layout to kill the 8-way
// bank conflict on frag ds_read_b128 (64B rows -> bank base (16r)%32 has only
// 2 values; 8 lanes per 4-bank group). phys_slot = s ^ ((row>>1)&3) spreads
// 16 lanes over 8 positions (2-way = free, m136). Staging keeps the LINEAR
// global_load_lds dest and pre-swizzles the GLOBAL source slot (rule #21 /
// m173: both-sides-or-neither, source and read use the same involution).
__global__ __launch_bounds__(256, 4) void k_gemm(const short* __restrict__ Xt,
                                                 const float* __restrict__ nrm2p,
                                                 float* __restrict__ out) {
  const int bid = blockIdx.x;
  const int xcd = bid & 7;
  const int s = bid >> 3;              // 0..271
  const int b = xcd * 2 + (s >= NT);   // 2 batches per XCD
  int t = s - (s >= NT ? NT : 0);      // 0..135

  int tm, tn;
  if (t < NT_OFF) {
    int rem = t, len = 15;
    tm = 0;
    while (rem >= len) { rem -= len; --len; ++tm; }
    tn = tm + 1 + rem;
  } else {
    tm = tn = t - NT_OFF;
  }
  const int p0 = tm * 128, q0 = tn * 128;
  const short* Xb = Xt + (size_t)b * P_ * C_;

  __shared__ __align__(16) char smem[32768];  // As[2][8K] | Bs[2][8K]; epilogue reuse

  const int tid = threadIdx.x;
  const int lane = tid & 63;
  const int wid = tid >> 6;
  const int wrow = wid >> 1;
  const int wcol = wid & 1;

  floatx4 acc[4][4];
#pragma unroll
  for (int i = 0; i < 4; ++i)
#pragma unroll
    for (int j = 0; j < 4; ++j) acc[i][j] = (floatx4){0.f, 0.f, 0.f, 0.f};

  const int K2 = C_ * 2;  // row stride bytes

  auto STAGE = [&](int buf, int kt) {
    const int kb = kt * (BK * 2);
#pragma unroll
    for (int j = 0; j < 2; ++j) {
      const int chunk = j * 4 + wid;           // 0..7, wave-uniform
      const int f = chunk * 1024 + lane * 16;  // linear LDS dest byte
      const int row = f >> 6;                  // 64B per row
      const int sphys = (f >> 4) & 3;          // 16B slot the HW will write
      const int slog = sphys ^ ((row >> 1) & 3);  // pre-swizzled source slot
      GLOAD_LDS16((const char*)Xb + (size_t)(p0 + row) * K2 + kb + slog * 16,
                  smem + buf * 8192 + chunk * 1024);
      GLOAD_LDS16((const char*)Xb + (size_t)(q0 + row) * K2 + kb + slog * 16,
                  smem + 16384 + buf * 8192 + chunk * 1024);
    }
  };

  STAGE(0, 0);

  // r6/r12's proven loop: counted vmcnt (never drained mid-loop) + the
  // lgkmcnt(0)-before-restage-barrier completion discipline.
  for (int kt = 0; kt < KT; ++kt) {
    const int cur = kt & 1;
    if (kt < KT - 1) {
      STAGE(cur ^ 1, kt + 1);
      asm volatile("s_waitcnt vmcnt(4)\n\ts_barrier" ::: "memory");
    } else {
      asm volatile("s_waitcnt vmcnt(0)\n\ts_barrier" ::: "memory");
    }

    const short* As = (const short*)(smem + cur * 8192);
    const short* Bs = (const short*)(smem + 16384 + cur * 8192);
    short8 af[4], bf[4];
#pragma unroll
    for (int mi = 0; mi < 4; ++mi) {
      const int r = wrow * 64 + mi * 16 + (lane & 15);
      const int sp = (lane >> 4) ^ ((r >> 1) & 3);  // swizzled slot
      af[mi] = *reinterpret_cast<const short8*>(&As[r * BK + sp * 8]);
    }
#pragma unroll
    for (int ni = 0; ni < 4; ++ni) {
      const int r = wcol * 64 + ni * 16 + (lane & 15);
      const int sp = (lane >> 4) ^ ((r >> 1) & 3);
      bf[ni] = *reinterpret_cast<const short8*>(&Bs[r * BK + sp * 8]);
    }
    // D[row=p][col=q]; C/D layout: col=lane&15, row=(lane>>4)*4+reg (verified r1)
#pragma unroll
    for (int mi = 0; mi < 4; ++mi)
#pragma unroll
      for (int ni = 0; ni < 4; ++ni)
        acc[mi][ni] = __builtin_amdgcn_mfma_f32_16x16x32_bf16(af[mi], bf[ni], acc[mi][ni], 0, 0, 0);

    asm volatile("s_waitcnt lgkmcnt(0)\n\ts_barrier" ::: "memory");
  }

  // ---- epilogue (identical to r12) ----
  const float* n2a = nrm2p + (size_t)b * P_;
  const float* n2b = nrm2p + (size_t)B_ * P_ + (size_t)b * P_;
  float* ob = out + (size_t)b * P_ * P_;
  const int cl = lane & 15, rg4 = (lane >> 4) * 4;

  float rnq[4];
#pragma unroll
  for (int ni = 0; ni < 4; ++ni) {
    const int qc = q0 + wcol * 64 + ni * 16 + cl;
    rnq[ni] = __builtin_amdgcn_rcpf(fmaxf(sqrtf(n2a[qc] + n2b[qc]), 1e-4f));
  }
  floatx4 rnp[4];
#pragma unroll
  for (int mi = 0; mi < 4; ++mi) {
    const int pb = p0 + wrow * 64 + mi * 16 + rg4;
    const float4 pa = *reinterpret_cast<const float4*>(&n2a[pb]);
    const float4 pbv = *reinterpret_cast<const float4*>(&n2b[pb]);
    rnp[mi][0] = __builtin_amdgcn_rcpf(fmaxf(sqrtf(pa.x + pbv.x), 1e-4f));
    rnp[mi][1] = __builtin_amdgcn_rcpf(fmaxf(sqrtf(pa.y + pbv.y), 1e-4f));
    rnp[mi][2] = __builtin_amdgcn_rcpf(fmaxf(sqrtf(pa.z + pbv.z), 1e-4f));
    rnp[mi][3] = __builtin_amdgcn_rcpf(fmaxf(sqrtf(pa.w + pbv.w), 1e-4f));
  }

  float* etile = (float*)smem + wid * 1280;  // per-wave [64 q][20 p] bounce

#pragma unroll
  for (int mi = 0; mi < 4; ++mi) {
    const int prow = p0 + wrow * 64 + mi * 16 + rg4;
#pragma unroll
    for (int ni = 0; ni < 4; ++ni) {
      floatx4 vv = acc[mi][ni] * rnp[mi] * rnq[ni];
      const int qc = q0 + wcol * 64 + ni * 16 + cl;
      if (tm == tn) {
        const int d = qc - prow;
        if (d >= 0 && d < 4) vv[d] = 1.0f;
      }
      ob[(size_t)(prow + 0) * P_ + qc] = vv[0];
      ob[(size_t)(prow + 1) * P_ + qc] = vv[1];
      ob[(size_t)(prow + 2) * P_ + qc] = vv[2];
      ob[(size_t)(prow + 3) * P_ + qc] = vv[3];
      if (tm != tn)
        *reinterpret_cast<floatx4*>(&etile[(ni * 16 + cl) * 20 + rg4]) = vv;
    }
    if (tm != tn) {
      const int pcb = p0 + wrow * 64 + mi * 16;
#pragma unroll
      for (int i = 0; i < 4; ++i) {
        const int qq = i * 16 + (lane >> 2);
        const floatx4 mv = *reinterpret_cast<const floatx4*>(&etile[qq * 20 + (lane & 3) * 4]);
        *reinterpret_cast<floatx4*>(
            &ob[(size_t)(q0 + wcol * 64 + qq) * P_ + pcb + (lane & 3) * 4]) = mv;
      }
    }
  }
}

extern "C" void kernel_launch(void* const* d_in, const int* in_sizes, int n_in,
                              void* d_out, int out_size, void* d_ws, size_t ws_size,
                              hipStream_t stream) {
  const float* x = (const float*)d_in[0];
  float* out = (float*)d_out;

  short* Xt = (short*)d_ws;                                                     // 16 MB
  float* nrm2p = (float*)((char*)d_ws + (size_t)B_ * P_ * C_ * sizeof(short));  // 2x128 KB

  k_transpose<<<dim3(P_ / 128, B_, 2), 256, 0, stream>>>(x, Xt, nrm2p);
  k_gemm<<<dim3(NT * B_), 256, 0, stream>>>(Xt, nrm2p, out);
}